// Round 13
// baseline (87.342 us; speedup 1.0000x reference)
//
#include <hip/hip_runtime.h>
#include <hip/hip_fp16.h>

#define HIDDEN 32
#define NOUT 9

typedef float    f4 __attribute__((ext_vector_type(4)));
typedef unsigned u2 __attribute__((ext_vector_type(2)));

__device__ __forceinline__ float fast_tanh(float v) {
    float e = __expf(2.0f * v);
    return 1.0f - __fdividef(2.0f, e + 1.0f);
}
__device__ __forceinline__ unsigned pack2f(float a, float b) {
    unsigned lo = __half_as_ushort(__float2half(a));
    unsigned hi = __half_as_ushort(__float2half(b));
    return lo | (hi << 16);
}
__device__ __forceinline__ float2 up2(unsigned u) {
    union { unsigned u; __half2 h; } cv; cv.u = u;
    return __half22float2(cv.h);
}

// ---- 9 x 14-bit fields packed in 16 B; field j at global bits [14j,14j+14) --
__device__ __forceinline__ uint4 pack9q(const unsigned* f) {
    uint4 r;
    r.x = f[0] | (f[1] << 14) | (f[2] << 28);
    r.y = (f[2] >> 4) | (f[3] << 10) | (f[4] << 24);
    r.z = (f[4] >> 8) | (f[5] << 6) | (f[6] << 20);
    r.w = (f[6] >> 12) | (f[7] << 2) | (f[8] << 16);
    return r;
}
__device__ __forceinline__ unsigned ext14(const uint4& v, int j) {
    const int bit = 14 * j;
    if (bit + 14 <= 64) {
        unsigned long long u = ((unsigned long long)v.y << 32) | v.x;
        return (unsigned)(u >> bit) & 0x3FFFu;
    } else if (bit < 64) {  // j == 4
        unsigned long long u = ((unsigned long long)v.z << 32) | v.y;
        return (unsigned)(u >> (bit - 32)) & 0x3FFFu;
    } else {
        unsigned long long u = ((unsigned long long)v.w << 32) | v.z;
        return (unsigned)(u >> (bit - 64)) & 0x3FFFu;
    }
}
// table quant: q = round(y*1024)+8192, y clamped +-7.99 (values ~N(0,0.57))
__device__ __forceinline__ unsigned q14(float y) {
    float t = fminf(fmaxf(y, -7.99f), 7.99f);
    return (unsigned)(__float2int_rn(t * 1024.f) + 8192);
}

// ---- pass 0: both tables, NORMAL stores (tables must stay cache-warm) ------
__global__ __launch_bounds__(256) void precompute_kernel(
    const float* __restrict__ x, const float* __restrict__ W,
    uint4* __restrict__ ys16, uint4* __restrict__ yd16, int NR)
{
    __shared__ float XL[256 * 33];
    __shared__ float Wl[NOUT * 64];
    for (int i = threadIdx.x; i < NOUT * 64; i += 256) Wl[i] = W[i];

    const int base = blockIdx.x * 256;
    const f4* Xv = (const f4*)x;
    #pragma unroll
    for (int i = 0; i < 8; ++i) {
        int fi = i * 256 + threadIdx.x;
        int row = fi >> 3, ch = fi & 7;
        f4 v = {0.f, 0.f, 0.f, 0.f};
        if (base + row < NR)
            v = __builtin_nontemporal_load(Xv + (size_t)(base + row) * 8 + ch);
        float* p = &XL[row * 33 + ch * 4];
        p[0] = v.x; p[1] = v.y; p[2] = v.z; p[3] = v.w;
    }
    __syncthreads();

    const int row = base + threadIdx.x;
    if (row >= NR) return;

    float ys[NOUT], yd[NOUT];
    #pragma unroll
    for (int j = 0; j < NOUT; ++j) { ys[j] = 0.f; yd[j] = 0.f; }
    const float* xr = &XL[threadIdx.x * 33];
    #pragma unroll
    for (int c = 0; c < 32; ++c) {
        float xv = xr[c];
        #pragma unroll
        for (int j = 0; j < NOUT; ++j) {
            ys[j] += xv * Wl[j * 64 + c];
            yd[j] += xv * Wl[j * 64 + 32 + c];
        }
    }
    unsigned fs[NOUT], fd[NOUT];
    #pragma unroll
    for (int j = 0; j < NOUT; ++j) { fs[j] = q14(ys[j]); fd[j] = q14(yd[j]); }
    ys16[row] = pack9q(fs);   // normal store: table must stay L2/L3-resident
    yd16[row] = pack9q(fd);
}

// ---- pass A (verbatim R6): 1 group/thread, 3 src gathers -> planar partial --
__global__ __launch_bounds__(256) void passA_kernel(
    const uint4* __restrict__ ys16, const int* __restrict__ ei,
    unsigned* __restrict__ pw,          // 4 dword planes, each [G]
    unsigned short* __restrict__ ph,    // fp16 plane [G]
    int G)
{
    int g = blockIdx.x * 256 + threadIdx.x;
    if (g >= G) return;
    const int* sp = ei + 3 * (size_t)g;
    int s0 = __builtin_nontemporal_load(sp);
    int s1 = __builtin_nontemporal_load(sp + 1);
    int s2 = __builtin_nontemporal_load(sp + 2);

    uint4 A0 = ys16[s0], A1 = ys16[s1], A2 = ys16[s2];

    float c[NOUT];
    #pragma unroll
    for (int j = 0; j < NOUT; ++j) {
        unsigned e = ext14(A0, j) + ext14(A1, j) + ext14(A2, j);
        c[j] = (float)(int)e * (1.f / 1024.f) - 24.f;   // 3*8192/1024
    }

    __builtin_nontemporal_store(pack2f(c[0], c[1]), pw + g);
    __builtin_nontemporal_store(pack2f(c[2], c[3]), pw + (size_t)G + g);
    __builtin_nontemporal_store(pack2f(c[4], c[5]), pw + 2 * (size_t)G + g);
    __builtin_nontemporal_store(pack2f(c[6], c[7]), pw + 3 * (size_t)G + g);
    __builtin_nontemporal_store(__half_as_ushort(__float2half(c[8])), ph + g);
}

// ---- pass B: 2 groups/thread, 6 gathers + paired partial loads in flight ---
__global__ __launch_bounds__(256) void passB_kernel(
    const uint4* __restrict__ yd16, const int* __restrict__ ei,
    const unsigned* __restrict__ pw, const unsigned short* __restrict__ ph,
    float* __restrict__ out, int G, int E)
{
    __shared__ float OL[256 * 18];
    const int t = threadIdx.x;
    const int T = blockIdx.x * 256 + t;
    const int g0 = 2 * T, g1 = 2 * T + 1;

    if (g0 < G) {
        const bool has1 = (g1 < G);
        const int* dp = ei + (size_t)E + 3 * (size_t)g0;  // 6 consecutive ints
        int d0 = __builtin_nontemporal_load(dp);
        int d1 = __builtin_nontemporal_load(dp + 1);
        int d2 = __builtin_nontemporal_load(dp + 2);
        int d3 = has1 ? __builtin_nontemporal_load(dp + 3) : 0;
        int d4 = has1 ? __builtin_nontemporal_load(dp + 4) : 0;
        int d5 = has1 ? __builtin_nontemporal_load(dp + 5) : 0;

        // 6 random 16B gathers in flight
        uint4 B0 = yd16[d0], B1 = yd16[d1], B2 = yd16[d2];
        uint4 B3 = yd16[d3], B4 = yd16[d4], B5 = yd16[d5];

        // paired partial loads: (g0,g1) adjacent in each plane -> 8B vectors
        u2 pq0 = __builtin_nontemporal_load((const u2*)(pw + g0));
        u2 pq1 = __builtin_nontemporal_load((const u2*)(pw + (size_t)G + g0));
        u2 pq2 = __builtin_nontemporal_load((const u2*)(pw + 2 * (size_t)G + g0));
        u2 pq3 = __builtin_nontemporal_load((const u2*)(pw + 3 * (size_t)G + g0));
        unsigned pq4 = __builtin_nontemporal_load(
                           (const unsigned*)(ph + g0));  // two fp16

        float c0[NOUT], c1[NOUT];
        float2 tt;
        tt = up2(pq0.x); c0[0] = tt.x; c0[1] = tt.y;
        tt = up2(pq1.x); c0[2] = tt.x; c0[3] = tt.y;
        tt = up2(pq2.x); c0[4] = tt.x; c0[5] = tt.y;
        tt = up2(pq3.x); c0[6] = tt.x; c0[7] = tt.y;
        tt = up2(pq0.y); c1[0] = tt.x; c1[1] = tt.y;
        tt = up2(pq1.y); c1[2] = tt.x; c1[3] = tt.y;
        tt = up2(pq2.y); c1[4] = tt.x; c1[5] = tt.y;
        tt = up2(pq3.y); c1[6] = tt.x; c1[7] = tt.y;
        tt = up2(pq4);   c0[8] = tt.x; c1[8] = tt.y;

        #pragma unroll
        for (int j = 0; j < NOUT; ++j) {
            unsigned e0 = ext14(B0, j) + ext14(B1, j) + ext14(B2, j);
            unsigned e1 = ext14(B3, j) + ext14(B4, j) + ext14(B5, j);
            c0[j] += (float)(int)e0 * (1.f / 1024.f) - 24.f;
            c1[j] += (float)(int)e1 * (1.f / 1024.f) - 24.f;
        }

        float* o = &OL[t * 18];
        #pragma unroll
        for (int j = 0; j < NOUT; ++j) {
            o[j]     = fast_tanh(c0[j]);
            o[9 + j] = has1 ? fast_tanh(c1[j]) : 0.f;
        }
    } else {
        float* o = &OL[t * 18];
        #pragma unroll
        for (int j = 0; j < 18; ++j) o[j] = 0.f;
    }
    __syncthreads();

    const size_t base = (size_t)blockIdx.x * 256 * 18;
    const size_t lim  = (size_t)G * 9;
    #pragma unroll
    for (int k = 0; k < 18; ++k) {
        size_t d = base + (size_t)k * 256 + t;
        if (d < lim)
            __builtin_nontemporal_store(OL[k * 256 + t], out + d);
    }
}

// ---- fallback 1: one-pass gather (small ws) --------------------------------
__global__ __launch_bounds__(256) void gather1_kernel(
    const uint4* __restrict__ ys16, const uint4* __restrict__ yd16,
    const int* __restrict__ ei, float* __restrict__ out, int G, int E)
{
    int g = blockIdx.x * 256 + threadIdx.x;
    if (g >= G) return;
    const int* sp = ei + 3 * (size_t)g;
    const int* dp = ei + (size_t)E + 3 * (size_t)g;
    int s0 = sp[0], s1 = sp[1], s2 = sp[2];
    int d0 = dp[0], d1 = dp[1], d2 = dp[2];
    uint4 A0 = ys16[s0], A1 = ys16[s1], A2 = ys16[s2];
    uint4 B0 = yd16[d0], B1 = yd16[d1], B2 = yd16[d2];
    float* o = out + (size_t)g * 9;
    #pragma unroll
    for (int j = 0; j < NOUT; ++j) {
        unsigned e = ext14(A0, j) + ext14(A1, j) + ext14(A2, j)
                   + ext14(B0, j) + ext14(B1, j) + ext14(B2, j);
        o[j] = fast_tanh((float)(int)e * (1.f / 1024.f) - 48.f);
    }
}

// ---- fallback 2: monolithic, no workspace ----------------------------------
__device__ __forceinline__ float dot4(float4 a, float4 b) {
    return a.x * b.x + a.y * b.y + a.z * b.z + a.w * b.w;
}
__global__ __launch_bounds__(256) void sheaf_fallback(
    const float* __restrict__ x, const int* __restrict__ edge_index,
    const float* __restrict__ W, float* __restrict__ out, int G, int E)
{
    __shared__ float Wlds[NOUT * 64];
    for (int i = threadIdx.x; i < NOUT * 64; i += 256) Wlds[i] = W[i];
    __syncthreads();
    const int l = threadIdx.x & 7;
    const int s = (blockIdx.x * 256 + threadIdx.x) >> 3;
    const int g0 = 2 * s, g1 = 2 * s + 1;
    if (g0 >= G) return;
    const bool has1 = (g1 < G);
    const float4* Xv = reinterpret_cast<const float4*>(x);
    const float4* Wv = reinterpret_cast<const float4*>(Wlds);
    const int* sp = edge_index + 3 * g0;
    const int* dp = edge_index + E + 3 * g0;
    int s0 = sp[0], s1 = sp[1], s2 = sp[2], d0 = dp[0], d1 = dp[1], d2 = dp[2];
    int s3 = 0, s4 = 0, s5 = 0, d3 = 0, d4 = 0, d5 = 0;
    if (has1) { s3 = sp[3]; s4 = sp[4]; s5 = sp[5]; d3 = dp[3]; d4 = dp[4]; d5 = dp[5]; }
    float4 a0 = Xv[s0 * 8 + l], a1 = Xv[s1 * 8 + l], a2 = Xv[s2 * 8 + l];
    float4 b0 = Xv[d0 * 8 + l], b1 = Xv[d1 * 8 + l], b2 = Xv[d2 * 8 + l];
    float4 a3 = Xv[s3 * 8 + l], a4 = Xv[s4 * 8 + l], a5 = Xv[s5 * 8 + l];
    float4 b3 = Xv[d3 * 8 + l], b4 = Xv[d4 * 8 + l], b5 = Xv[d5 * 8 + l];
    float4 xs0, xd0, xs1, xd1;
    xs0.x = a0.x + a1.x + a2.x; xs0.y = a0.y + a1.y + a2.y;
    xs0.z = a0.z + a1.z + a2.z; xs0.w = a0.w + a1.w + a2.w;
    xd0.x = b0.x + b1.x + b2.x; xd0.y = b0.y + b1.y + b2.y;
    xd0.z = b0.z + b1.z + b2.z; xd0.w = b0.w + b1.w + b2.w;
    xs1.x = a3.x + a4.x + a5.x; xs1.y = a3.y + a4.y + a5.y;
    xs1.z = a3.z + a4.z + a5.z; xs1.w = a3.w + a4.w + a5.w;
    xd1.x = b3.x + b4.x + b5.x; xd1.y = b3.y + b4.y + b5.y;
    xd1.z = b3.z + b4.z + b5.z; xd1.w = b3.w + b4.w + b5.w;
    float my0 = 0.f, ex0 = 0.f, my1 = 0.f, ex1 = 0.f;
    #pragma unroll
    for (int j = 0; j < NOUT; ++j) {
        float4 ws = Wv[j * 16 + l];
        float4 wd = Wv[j * 16 + 8 + l];
        float t0 = dot4(xs0, ws) + dot4(xd0, wd);
        float t1 = dot4(xs1, ws) + dot4(xd1, wd);
        t0 += __shfl_xor(t0, 1); t1 += __shfl_xor(t1, 1);
        t0 += __shfl_xor(t0, 2); t1 += __shfl_xor(t1, 2);
        t0 += __shfl_xor(t0, 4); t1 += __shfl_xor(t1, 4);
        if (j < 8) { if (l == j) { my0 = t0; my1 = t1; } }
        else { ex0 = t0; ex1 = t1; }
    }
    out[g0 * 9 + l] = fast_tanh(my0);
    if (l == 0) out[g0 * 9 + 8] = fast_tanh(ex0);
    if (has1) {
        out[g1 * 9 + l] = fast_tanh(my1);
        if (l == 0) out[g1 * 9 + 8] = fast_tanh(ex1);
    }
}

extern "C" void kernel_launch(void* const* d_in, const int* in_sizes, int n_in,
                              void* d_out, int out_size, void* d_ws, size_t ws_size,
                              hipStream_t stream) {
    const float* x   = (const float*)d_in[0];
    const int*   ei  = (const int*)d_in[1];
    const float* W   = (const float*)d_in[2];
    float*       out = (float*)d_out;

    const int NR = in_sizes[0] / HIDDEN;  // 300,000
    const int E  = in_sizes[1] / 2;       // 3,000,000
    const int G  = E / 3;                 // 1,000,000

    char* ws = (char*)d_ws;
    const size_t o_ys = 0;
    const size_t o_yd = o_ys + (size_t)NR * 16;
    const size_t o_pw = o_yd + (size_t)NR * 16;
    const size_t o_ph = o_pw + (size_t)G * 16;        // 4 dword planes
    const size_t need_two = o_ph + (size_t)G * 2;     // ~27.6 MB
    const size_t need_one = o_pw;                     // ~9.6 MB

    uint4*          ys16 = (uint4*)(ws + o_ys);
    uint4*          yd16 = (uint4*)(ws + o_yd);
    unsigned*       pw   = (unsigned*)(ws + o_pw);
    unsigned short* ph   = (unsigned short*)(ws + o_ph);

    const int PB  = (NR + 255) / 256;            // pre blocks
    const int GB  = (G + 255) / 256;             // passA blocks (1 group/thr)
    const int GB2 = ((G + 1) / 2 + 255) / 256;   // passB blocks (2 groups/thr)

    if (ws_size >= need_two) {
        hipLaunchKernelGGL(precompute_kernel, dim3(PB), dim3(256), 0, stream,
                           x, W, ys16, yd16, NR);
        hipLaunchKernelGGL(passA_kernel, dim3(GB), dim3(256), 0, stream,
                           ys16, ei, pw, ph, G);
        hipLaunchKernelGGL(passB_kernel, dim3(GB2), dim3(256), 0, stream,
                           yd16, ei, pw, ph, out, G, E);
    } else if (ws_size >= need_one) {
        hipLaunchKernelGGL(precompute_kernel, dim3(PB), dim3(256), 0, stream,
                           x, W, ys16, yd16, NR);
        hipLaunchKernelGGL(gather1_kernel, dim3(GB), dim3(256), 0, stream,
                           ys16, yd16, ei, out, G, E);
    } else {
        const int subwaves = (G + 1) / 2;
        const int blocks   = (subwaves + 31) / 32;
        hipLaunchKernelGGL(sheaf_fallback, dim3(blocks), dim3(256), 0, stream,
                           x, ei, W, out, G, E);
    }
}

// Round 14
// 82.561 us; speedup vs baseline: 1.0579x; 1.0579x over previous
//
#include <hip/hip_runtime.h>
#include <hip/hip_fp16.h>

#define HIDDEN 32
#define NOUT 9

typedef float f4 __attribute__((ext_vector_type(4)));

__device__ __forceinline__ float fast_tanh(float v) {
    float e = __expf(2.0f * v);
    return 1.0f - __fdividef(2.0f, e + 1.0f);
}
__device__ __forceinline__ unsigned pack2f(float a, float b) {
    unsigned lo = __half_as_ushort(__float2half(a));
    unsigned hi = __half_as_ushort(__float2half(b));
    return lo | (hi << 16);
}
__device__ __forceinline__ float2 up2(unsigned u) {
    union { unsigned u; __half2 h; } cv; cv.u = u;
    return __half22float2(cv.h);
}

// ---- 9 x 14-bit fields packed in 16 B; field j at global bits [14j,14j+14) --
__device__ __forceinline__ uint4 pack9q(const unsigned* f) {
    uint4 r;
    r.x = f[0] | (f[1] << 14) | (f[2] << 28);
    r.y = (f[2] >> 4) | (f[3] << 10) | (f[4] << 24);
    r.z = (f[4] >> 8) | (f[5] << 6) | (f[6] << 20);
    r.w = (f[6] >> 12) | (f[7] << 2) | (f[8] << 16);
    return r;
}
__device__ __forceinline__ unsigned ext14(const uint4& v, int j) {
    const int bit = 14 * j;
    if (bit + 14 <= 64) {
        unsigned long long u = ((unsigned long long)v.y << 32) | v.x;
        return (unsigned)(u >> bit) & 0x3FFFu;
    } else if (bit < 64) {  // j == 4
        unsigned long long u = ((unsigned long long)v.z << 32) | v.y;
        return (unsigned)(u >> (bit - 32)) & 0x3FFFu;
    } else {
        unsigned long long u = ((unsigned long long)v.w << 32) | v.z;
        return (unsigned)(u >> (bit - 64)) & 0x3FFFu;
    }
}
// table quant: q = round(y*1024)+8192, y clamped +-7.99 (values ~N(0,0.57))
__device__ __forceinline__ unsigned q14(float y) {
    float t = fminf(fmaxf(y, -7.99f), 7.99f);
    return (unsigned)(__float2int_rn(t * 1024.f) + 8192);
}

// ---- pass 0: per-row y = [W_src@x_i (9) | W_dst@x_i (9)], 16B packed rows --
__global__ __launch_bounds__(256) void precompute_kernel(
    const float* __restrict__ x, const float* __restrict__ W,
    uint4* __restrict__ ys16, uint4* __restrict__ yd16, int NR)
{
    __shared__ float XL[256 * 33];
    __shared__ float Wl[NOUT * 64];
    for (int i = threadIdx.x; i < NOUT * 64; i += 256) Wl[i] = W[i];

    const int base = blockIdx.x * 256;
    const f4* Xv = (const f4*)x;
    #pragma unroll
    for (int i = 0; i < 8; ++i) {
        int fi = i * 256 + threadIdx.x;
        int row = fi >> 3, ch = fi & 7;
        f4 v = {0.f, 0.f, 0.f, 0.f};
        if (base + row < NR)
            v = __builtin_nontemporal_load(Xv + (size_t)(base + row) * 8 + ch);
        float* p = &XL[row * 33 + ch * 4];
        p[0] = v.x; p[1] = v.y; p[2] = v.z; p[3] = v.w;
    }
    __syncthreads();

    const int row = base + threadIdx.x;
    if (row >= NR) return;

    float ys[NOUT], yd[NOUT];
    #pragma unroll
    for (int j = 0; j < NOUT; ++j) { ys[j] = 0.f; yd[j] = 0.f; }
    const float* xr = &XL[threadIdx.x * 33];
    #pragma unroll
    for (int c = 0; c < 32; ++c) {
        float xv = xr[c];
        #pragma unroll
        for (int j = 0; j < NOUT; ++j) {
            ys[j] += xv * Wl[j * 64 + c];
            yd[j] += xv * Wl[j * 64 + 32 + c];
        }
    }
    unsigned fs[NOUT], fd[NOUT];
    #pragma unroll
    for (int j = 0; j < NOUT; ++j) { fs[j] = q14(ys[j]); fd[j] = q14(yd[j]); }
    ys16[row] = pack9q(fs);   // normal store: tables must stay cache-warm
    yd16[row] = pack9q(fd);
}

// ---- pass A: src gathers (ONE uint4 per endpoint) -> planar fp16 partials --
__global__ __launch_bounds__(256) void passA_kernel(
    const uint4* __restrict__ ys16, const int* __restrict__ ei,
    unsigned* __restrict__ pw,          // 4 dword planes, each [G]
    unsigned short* __restrict__ ph,    // fp16 plane [G]
    int G)
{
    int g = blockIdx.x * 256 + threadIdx.x;
    if (g >= G) return;
    const int* sp = ei + 3 * (size_t)g;
    int s0 = __builtin_nontemporal_load(sp);
    int s1 = __builtin_nontemporal_load(sp + 1);
    int s2 = __builtin_nontemporal_load(sp + 2);

    uint4 A0 = ys16[s0], A1 = ys16[s1], A2 = ys16[s2];

    float c[NOUT];
    #pragma unroll
    for (int j = 0; j < NOUT; ++j) {
        unsigned e = ext14(A0, j) + ext14(A1, j) + ext14(A2, j);
        c[j] = (float)(int)e * (1.f / 1024.f) - 24.f;   // 3*8192/1024
    }

    __builtin_nontemporal_store(pack2f(c[0], c[1]), pw + g);
    __builtin_nontemporal_store(pack2f(c[2], c[3]), pw + (size_t)G + g);
    __builtin_nontemporal_store(pack2f(c[4], c[5]), pw + 2 * (size_t)G + g);
    __builtin_nontemporal_store(pack2f(c[6], c[7]), pw + 3 * (size_t)G + g);
    __builtin_nontemporal_store(__half_as_ushort(__float2half(c[8])), ph + g);
}

// ---- pass B: dst gathers + partials + tanh, LDS-staged coalesced out -------
__global__ __launch_bounds__(256) void passB_kernel(
    const uint4* __restrict__ yd16, const int* __restrict__ ei,
    const unsigned* __restrict__ pw, const unsigned short* __restrict__ ph,
    float* __restrict__ out, int G, int E)
{
    __shared__ float OL[256 * 9];
    const int t = threadIdx.x;
    const int g = blockIdx.x * 256 + t;

    if (g < G) {
        const int* dp = ei + (size_t)E + 3 * (size_t)g;
        int d0 = __builtin_nontemporal_load(dp);
        int d1 = __builtin_nontemporal_load(dp + 1);
        int d2 = __builtin_nontemporal_load(dp + 2);

        uint4 B0 = yd16[d0], B1 = yd16[d1], B2 = yd16[d2];

        unsigned pq0 = __builtin_nontemporal_load(pw + g);
        unsigned pq1 = __builtin_nontemporal_load(pw + (size_t)G + g);
        unsigned pq2 = __builtin_nontemporal_load(pw + 2 * (size_t)G + g);
        unsigned pq3 = __builtin_nontemporal_load(pw + 3 * (size_t)G + g);
        unsigned short pq4 = __builtin_nontemporal_load(ph + g);

        float c[NOUT];
        float2 tt;
        tt = up2(pq0); c[0] = tt.x; c[1] = tt.y;
        tt = up2(pq1); c[2] = tt.x; c[3] = tt.y;
        tt = up2(pq2); c[4] = tt.x; c[5] = tt.y;
        tt = up2(pq3); c[6] = tt.x; c[7] = tt.y;
        c[8] = __half2float(__ushort_as_half(pq4));

        #pragma unroll
        for (int j = 0; j < NOUT; ++j) {
            unsigned e = ext14(B0, j) + ext14(B1, j) + ext14(B2, j);
            c[j] += (float)(int)e * (1.f / 1024.f) - 24.f;
        }

        float* o = &OL[t * 9];
        #pragma unroll
        for (int j = 0; j < NOUT; ++j) o[j] = fast_tanh(c[j]);
    } else {
        float* o = &OL[t * 9];
        #pragma unroll
        for (int j = 0; j < NOUT; ++j) o[j] = 0.f;
    }
    __syncthreads();

    const size_t base = (size_t)blockIdx.x * 256 * 9;
    const size_t lim  = (size_t)G * 9;
    #pragma unroll
    for (int k = 0; k < 9; ++k) {
        size_t d = base + (size_t)k * 256 + t;
        if (d < lim)
            __builtin_nontemporal_store(OL[k * 256 + t], out + d);
    }
}

// ---- fallback 1: one-pass gather over both packed tables -------------------
__global__ __launch_bounds__(256) void gather1_kernel(
    const uint4* __restrict__ ys16, const uint4* __restrict__ yd16,
    const int* __restrict__ ei, float* __restrict__ out, int G, int E)
{
    int g = blockIdx.x * 256 + threadIdx.x;
    if (g >= G) return;
    const int* sp = ei + 3 * (size_t)g;
    const int* dp = ei + (size_t)E + 3 * (size_t)g;
    int s0 = sp[0], s1 = sp[1], s2 = sp[2];
    int d0 = dp[0], d1 = dp[1], d2 = dp[2];
    uint4 A0 = ys16[s0], A1 = ys16[s1], A2 = ys16[s2];
    uint4 B0 = yd16[d0], B1 = yd16[d1], B2 = yd16[d2];
    float* o = out + (size_t)g * 9;
    #pragma unroll
    for (int j = 0; j < NOUT; ++j) {
        unsigned e = ext14(A0, j) + ext14(A1, j) + ext14(A2, j)
                   + ext14(B0, j) + ext14(B1, j) + ext14(B2, j);
        o[j] = fast_tanh((float)(int)e * (1.f / 1024.f) - 48.f);
    }
}

// ---- fallback 2: monolithic, no workspace ----------------------------------
__device__ __forceinline__ float dot4(float4 a, float4 b) {
    return a.x * b.x + a.y * b.y + a.z * b.z + a.w * b.w;
}
__global__ __launch_bounds__(256) void sheaf_fallback(
    const float* __restrict__ x, const int* __restrict__ edge_index,
    const float* __restrict__ W, float* __restrict__ out, int G, int E)
{
    __shared__ float Wlds[NOUT * 64];
    for (int i = threadIdx.x; i < NOUT * 64; i += 256) Wlds[i] = W[i];
    __syncthreads();
    const int l = threadIdx.x & 7;
    const int s = (blockIdx.x * 256 + threadIdx.x) >> 3;
    const int g0 = 2 * s, g1 = 2 * s + 1;
    if (g0 >= G) return;
    const bool has1 = (g1 < G);
    const float4* Xv = reinterpret_cast<const float4*>(x);
    const float4* Wv = reinterpret_cast<const float4*>(Wlds);
    const int* sp = edge_index + 3 * g0;
    const int* dp = edge_index + E + 3 * g0;
    int s0 = sp[0], s1 = sp[1], s2 = sp[2], d0 = dp[0], d1 = dp[1], d2 = dp[2];
    int s3 = 0, s4 = 0, s5 = 0, d3 = 0, d4 = 0, d5 = 0;
    if (has1) { s3 = sp[3]; s4 = sp[4]; s5 = sp[5]; d3 = dp[3]; d4 = dp[4]; d5 = dp[5]; }
    float4 a0 = Xv[s0 * 8 + l], a1 = Xv[s1 * 8 + l], a2 = Xv[s2 * 8 + l];
    float4 b0 = Xv[d0 * 8 + l], b1 = Xv[d1 * 8 + l], b2 = Xv[d2 * 8 + l];
    float4 a3 = Xv[s3 * 8 + l], a4 = Xv[s4 * 8 + l], a5 = Xv[s5 * 8 + l];
    float4 b3 = Xv[d3 * 8 + l], b4 = Xv[d4 * 8 + l], b5 = Xv[d5 * 8 + l];
    float4 xs0, xd0, xs1, xd1;
    xs0.x = a0.x + a1.x + a2.x; xs0.y = a0.y + a1.y + a2.y;
    xs0.z = a0.z + a1.z + a2.z; xs0.w = a0.w + a1.w + a2.w;
    xd0.x = b0.x + b1.x + b2.x; xd0.y = b0.y + b1.y + b2.y;
    xd0.z = b0.z + b1.z + b2.z; xd0.w = b0.w + b1.w + b2.w;
    xs1.x = a3.x + a4.x + a5.x; xs1.y = a3.y + a4.y + a5.y;
    xs1.z = a3.z + a4.z + a5.z; xs1.w = a3.w + a4.w + a5.w;
    xd1.x = b3.x + b4.x + b5.x; xd1.y = b3.y + b4.y + b5.y;
    xd1.z = b3.z + b4.z + b5.z; xd1.w = b3.w + b4.w + b5.w;
    float my0 = 0.f, ex0 = 0.f, my1 = 0.f, ex1 = 0.f;
    #pragma unroll
    for (int j = 0; j < NOUT; ++j) {
        float4 ws = Wv[j * 16 + l];
        float4 wd = Wv[j * 16 + 8 + l];
        float t0 = dot4(xs0, ws) + dot4(xd0, wd);
        float t1 = dot4(xs1, ws) + dot4(xd1, wd);
        t0 += __shfl_xor(t0, 1); t1 += __shfl_xor(t1, 1);
        t0 += __shfl_xor(t0, 2); t1 += __shfl_xor(t1, 2);
        t0 += __shfl_xor(t0, 4); t1 += __shfl_xor(t1, 4);
        if (j < 8) { if (l == j) { my0 = t0; my1 = t1; } }
        else { ex0 = t0; ex1 = t1; }
    }
    out[g0 * 9 + l] = fast_tanh(my0);
    if (l == 0) out[g0 * 9 + 8] = fast_tanh(ex0);
    if (has1) {
        out[g1 * 9 + l] = fast_tanh(my1);
        if (l == 0) out[g1 * 9 + 8] = fast_tanh(ex1);
    }
}

extern "C" void kernel_launch(void* const* d_in, const int* in_sizes, int n_in,
                              void* d_out, int out_size, void* d_ws, size_t ws_size,
                              hipStream_t stream) {
    const float* x   = (const float*)d_in[0];
    const int*   ei  = (const int*)d_in[1];
    const float* W   = (const float*)d_in[2];
    float*       out = (float*)d_out;

    const int NR = in_sizes[0] / HIDDEN;  // 300,000
    const int E  = in_sizes[1] / 2;       // 3,000,000
    const int G  = E / 3;                 // 1,000,000

    char* ws = (char*)d_ws;
    const size_t o_ys = 0;
    const size_t o_yd = o_ys + (size_t)NR * 16;
    const size_t o_pw = o_yd + (size_t)NR * 16;
    const size_t o_ph = o_pw + (size_t)G * 16;        // 4 dword planes
    const size_t need_two = o_ph + (size_t)G * 2;     // ~27.6 MB
    const size_t need_one = o_pw;                     // ~9.6 MB

    uint4*          ys16 = (uint4*)(ws + o_ys);
    uint4*          yd16 = (uint4*)(ws + o_yd);
    unsigned*       pw   = (unsigned*)(ws + o_pw);
    unsigned short* ph   = (unsigned short*)(ws + o_ph);

    const int PB = (NR + 255) / 256;
    const int GB = (G + 255) / 256;

    if (ws_size >= need_two) {
        hipLaunchKernelGGL(precompute_kernel, dim3(PB), dim3(256), 0, stream,
                           x, W, ys16, yd16, NR);
        hipLaunchKernelGGL(passA_kernel, dim3(GB), dim3(256), 0, stream,
                           ys16, ei, pw, ph, G);
        hipLaunchKernelGGL(passB_kernel, dim3(GB), dim3(256), 0, stream,
                           yd16, ei, pw, ph, out, G, E);
    } else if (ws_size >= need_one) {
        hipLaunchKernelGGL(precompute_kernel, dim3(PB), dim3(256), 0, stream,
                           x, W, ys16, yd16, NR);
        hipLaunchKernelGGL(gather1_kernel, dim3(GB), dim3(256), 0, stream,
                           ys16, yd16, ei, out, G, E);
    } else {
        const int subwaves = (G + 1) / 2;
        const int blocks   = (subwaves + 31) / 32;
        hipLaunchKernelGGL(sheaf_fallback, dim3(blocks), dim3(256), 0, stream,
                           x, ei, W, out, G, E);
    }
}